// Round 13
// baseline (138.561 us; speedup 1.0000x reference)
//
#include <hip/hip_runtime.h>
#include <math.h>
#include <stdint.h>

// Video Swin shifted-window attention, fully fused, one block per window.
// Round 13: R12 (78.9KB LDS -> 2 independent blocks/CU, 80% occupancy) plus:
//  - jt-streamed phase 2: C-operand loaded inside the QK MFMA loop (1 f32x4
//    live vs cvec[7]+bb[7] ~28 regs) -> less remat under the 64-reg cap
//  - s_setprio(1) around QK and PV MFMA clusters (T5; regime now matches
//    m191's independent-block attn case)
//  - prep grid 1024

#define LOG2E   1.4426950408889634f
#define MASKNEG (-144.26950408889634f)   // -100 * LOG2E

typedef __attribute__((ext_vector_type(8)))  short    bf16x8;
typedef __attribute__((ext_vector_type(4)))  float    f32x4;
typedef __attribute__((ext_vector_type(4)))  unsigned uint32x4;

__device__ __forceinline__ unsigned short cvt1(float f) {
    __bf16 h = (__bf16)f;
    return __builtin_bit_cast(unsigned short, h);
}
__device__ __forceinline__ unsigned cvt2(float lo, float hi) {
    return (unsigned)cvt1(lo) | ((unsigned)cvt1(hi) << 16);
}

// token region code for the shifted-window mask (WIN=(2,7,7), SHIFT=(1,3,3))
__device__ __forceinline__ int tok_code(int t) {
    int pd = t / 49;
    int r  = t - pd * 49;
    int ph = r / 7;
    int pw = r - ph * 7;
    return (pd >= 1 ? 1 : 0) | (ph >= 4 ? 2 : 0) | (pw >= 4 ? 4 : 0);
}

__device__ __forceinline__ float mterm(unsigned pk, int sh, unsigned ci, unsigned cls) {
    return ((((pk >> sh) & 255u) ^ ci) & cls) ? MASKNEG : 0.f;
}

// XOR-swizzled element offset, [rows][128]-bf16 tiles (16B chunks)
__device__ __forceinline__ int swz(int row, int col) {
    return row * 128 + (((col >> 3) ^ (row & 7)) << 3) + (col & 7);
}

// ---------------- prep: weights -> bf16, bias tables ----------------
template<bool BIG>
__global__ void prep_kernel(const float* __restrict__ qkv_w,
                            const float* __restrict__ proj_w,
                            const float* __restrict__ rpb_table,
                            const int*   __restrict__ rel_index,
                            unsigned short* __restrict__ wqkv,
                            unsigned short* __restrict__ wproj,
                            void* __restrict__ btab) {
    int tid = blockIdx.x * blockDim.x + threadIdx.x;
    int stride = gridDim.x * blockDim.x;
    for (int i = tid; i < 384 * 128; i += stride) wqkv[i]  = cvt1(qkv_w[i]);
    for (int i = tid; i < 128 * 128; i += stride) wproj[i] = cvt1(proj_w[i]);
    if constexpr (BIG) {
        // bm[cls 8][h 4][i 112][j 112] f32: (bias + mask)*LOG2E; j>=98 -> -inf
        float* bm = (float*)btab;
        for (int idx = tid; idx < 32 * 112 * 112; idx += stride) {
            int ch = idx / 12544; int r = idx - ch * 12544;
            int i  = r / 112;     int j = r - i * 112;
            int cls = ch >> 2, h = ch & 3;
            float v;
            if (i < 98) {
                if (j < 98) {
                    float bias = rpb_table[rel_index[i * 98 + j] * 4 + h];
                    bool  msk  = (((unsigned)tok_code(i) ^ (unsigned)tok_code(j)) & (unsigned)cls) != 0;
                    v = bias * LOG2E + (msk ? MASKNEG : 0.f);
                } else v = -INFINITY;
            } else v = 0.f;
            bm[idx] = v;
        }
    } else {
        unsigned short* biasL = (unsigned short*)btab;
        for (int idx = tid; idx < 4 * 112 * 112; idx += stride) {
            int h = idx / 12544; int r = idx - h * 12544;
            int i = r / 112;     int j = r - i * 112;
            float v;
            if (i < 98) v = (j < 98) ? rpb_table[rel_index[i * 98 + j] * 4 + h] * LOG2E
                                     : -INFINITY;
            else v = 0.f;
            biasL[idx] = cvt1(v);
        }
    }
}

// ---------------- main fused kernel ----------------
template<bool BIG>
__global__ __launch_bounds__(1024, 8)
void swin_main(const float* __restrict__ x,
               const float* __restrict__ qkv_b,
               const float* __restrict__ proj_b,
               const unsigned short* __restrict__ wqkv,
               const unsigned short* __restrict__ wproj,
               const void* __restrict__ btab,
               float* __restrict__ out)
{
    extern __shared__ unsigned short lds[];
    unsigned short* q_w  = lds;            // q[98][128] swz; O overwrites
    unsigned short* k_w  = lds + 12544;    // k[98][128] swz
    unsigned short* xv_w = lds + 25088;    // x[112][128] swz -> vT[128][112] linear; +16 pad
    // total 39440 ush = 78880 B -> 2 blocks/CU

    const int b    = blockIdx.x;
    const int tid  = threadIdx.x;
    const int wv   = tid >> 6;    // 0..15
    const int lane = tid & 63;
    const int l4   = lane >> 4;   // 0..3
    const int lc   = lane & 15;   // 0..15

    // zero the 16-ush fragment-wrap pad (stale inf/NaN x 0 = NaN poison)
    if (tid < 8) *(unsigned*)(xv_w + 14336 + tid * 2) = 0u;

    // stage x -> xv_w swz (pad rows 98..111 zeroed)
    {
        const float* xb = x + (size_t)b * 12544;
#pragma unroll
        for (int i = 0; i < 4; ++i) {
            int idx = tid + i * 1024;
            if (idx >= 3584) break;
            int tok = idx >> 5;
            int c   = (idx & 31) << 2;
            float4 v;
            if (tok < 98) v = *(const float4*)(xb + tok * 128 + c);
            else { v.x = 0.f; v.y = 0.f; v.z = 0.f; v.w = 0.f; }
            uint2 hv; hv.x = cvt2(v.x, v.y); hv.y = cvt2(v.z, v.w);
            *(uint2*)(xv_w + swz(tok, c)) = hv;
        }
    }
    __syncthreads();

    // ---- Phase 1A: q,k tiles (wave ct: q<8 scaled, k>=8) ----
    {
        const int ct = wv;
        bf16x8 wf[4];
        f32x4  bias;
        const unsigned short* wrow = wqkv + (ct * 16 + lc) * 128;
#pragma unroll
        for (int kt = 0; kt < 4; ++kt) wf[kt] = *(const bf16x8*)(wrow + kt * 32 + l4 * 8);
#pragma unroll
        for (int r = 0; r < 4; ++r) bias[r] = qkv_b[ct * 16 + l4 * 4 + r];
        const bool  isq = (ct < 8);
        const float qs  = 0.17677669529663689f * LOG2E;
#pragma unroll
        for (int t = 0; t < 7; ++t) {
            bf16x8 xf[4];
#pragma unroll
            for (int kt = 0; kt < 4; ++kt)
                xf[kt] = *(bf16x8*)(xv_w + swz(t * 16 + lc, kt * 32 + l4 * 8));
            f32x4 acc = bias;
#pragma unroll
            for (int kt = 0; kt < 4; ++kt)
                acc = __builtin_amdgcn_mfma_f32_16x16x32_bf16(wf[kt], xf[kt], acc, 0, 0, 0);
            int tok = t * 16 + lc;
            if (tok < 98) {
                if (isq) {
                    uint2 hv; hv.x = cvt2(acc[0] * qs, acc[1] * qs); hv.y = cvt2(acc[2] * qs, acc[3] * qs);
                    *(uint2*)(q_w + swz(tok, ct * 16 + l4 * 4)) = hv;
                } else {
                    uint2 hv; hv.x = cvt2(acc[0], acc[1]); hv.y = cvt2(acc[2], acc[3]);
                    *(uint2*)(k_w + swz(tok, (ct - 8) * 16 + l4 * 4)) = hv;
                }
            }
        }
    }

    // ---- Phase 1B: v tiles into registers (x still live) ----
    f32x4 vacc[4];
    const int vd = (wv >> 1) * 16;
    const int t0 = (wv & 1) ? 4 : 0;
    const int nt = (wv & 1) ? 3 : 4;
    {
        bf16x8 wf2[4];
        const unsigned short* wrow2 = wqkv + (256 + vd + lc) * 128;
#pragma unroll
        for (int kt = 0; kt < 4; ++kt) wf2[kt] = *(const bf16x8*)(wrow2 + kt * 32 + l4 * 8);
        f32x4 bias2;
#pragma unroll
        for (int r = 0; r < 4; ++r) bias2[r] = qkv_b[256 + vd + l4 * 4 + r];
#pragma unroll
        for (int ti = 0; ti < 4; ++ti) {
            if (ti >= nt) break;
            int t = t0 + ti;
            bf16x8 xf[4];
#pragma unroll
            for (int kt = 0; kt < 4; ++kt)
                xf[kt] = *(bf16x8*)(xv_w + swz(t * 16 + lc, kt * 32 + l4 * 8));
            f32x4 acc = bias2;
#pragma unroll
            for (int kt = 0; kt < 4; ++kt)
                acc = __builtin_amdgcn_mfma_f32_16x16x32_bf16(wf2[kt], xf[kt], acc, 0, 0, 0);
            vacc[ti] = acc;
        }
    }
    __syncthreads();   // all x reads complete

    // ---- Phase 1C: vT[128][112] linear over the x region ----
    {
#pragma unroll
        for (int ti = 0; ti < 4; ++ti) {
            if (ti >= nt) break;
            int tok = (t0 + ti) * 16 + lc;
            const int rb = vd + l4 * 4;
            xv_w[(rb + 0) * 112 + tok] = cvt1(vacc[ti][0]);
            xv_w[(rb + 1) * 112 + tok] = cvt1(vacc[ti][1]);
            xv_w[(rb + 2) * 112 + tok] = cvt1(vacc[ti][2]);
            xv_w[(rb + 3) * 112 + tok] = cvt1(vacc[ti][3]);
        }
    }
    __syncthreads();

    // ---- Phase 2: attention. 28 tasks over 16 waves, 2 passes (shfl-P) ----
    const int wi  = b & 255;
    const unsigned int cls =
        ((wi >> 6) == 3 ? 1u : 0u) | (((wi >> 3) & 7) == 7 ? 2u : 0u) | ((wi & 7) == 7 ? 4u : 0u);

    unsigned int jcp[7];   // packed region codes (small path only)
    if constexpr (!BIG) {
#pragma unroll
        for (int jt = 0; jt < 7; ++jt) {
            int jb = jt * 16 + l4 * 4;
            unsigned int p = 0;
#pragma unroll
            for (int r = 0; r < 4; ++r) p |= (unsigned)tok_code(jb + r < 98 ? jb + r : 0) << (8 * r);
            jcp[jt] = p;
        }
    }

    const int  srcA = ((l4 & 1) * 2) * 16 + lc;   // P-redistribution source lanes
    const int  srcB = srcA + 16;
    const bool phi  = (l4 >> 1) != 0;

    for (int pass = 0; pass < 2; ++pass) {
        int task = wv + (pass << 4);
        if (task >= 28) break;
        int h  = task / 7;
        int it = task - h * 7;
        const int i_tok = it * 16 + lc;
        const bf16x8 qfrag = *(bf16x8*)(q_w + swz(i_tok, h * 32 + l4 * 8));

        // jt-streamed QK: one C-operand live at a time (minimal reg pressure)
        f32x4 s[7];
        const float* bmrow = (const float*)btab + ((size_t)((int)cls * 4 + h) * 112 + i_tok) * 112;
        const unsigned short* brow = (const unsigned short*)btab + (h * 112 + i_tok) * 112;
        const unsigned int ci = (unsigned)tok_code(i_tok < 98 ? i_tok : 0);
        __builtin_amdgcn_s_setprio(1);
#pragma unroll
        for (int jt = 0; jt < 7; ++jt) {
            f32x4 c;
            if constexpr (BIG) {
                c = *(const f32x4*)(bmrow + jt * 16 + l4 * 4);
            } else {
                ushort4 bb = *(const ushort4*)(brow + jt * 16 + l4 * 4);
                c[0] = __builtin_bit_cast(float, (unsigned)bb.x << 16) + mterm(jcp[jt], 0,  ci, cls);
                c[1] = __builtin_bit_cast(float, (unsigned)bb.y << 16) + mterm(jcp[jt], 8,  ci, cls);
                c[2] = __builtin_bit_cast(float, (unsigned)bb.z << 16) + mterm(jcp[jt], 16, ci, cls);
                c[3] = __builtin_bit_cast(float, (unsigned)bb.w << 16) + mterm(jcp[jt], 24, ci, cls);
            }
            bf16x8 kfrag = *(bf16x8*)(k_w + swz(jt * 16 + lc, h * 32 + l4 * 8));
            s[jt] = __builtin_amdgcn_mfma_f32_16x16x32_bf16(kfrag, qfrag, c, 0, 0, 0);
        }
        __builtin_amdgcn_s_setprio(0);

        // no-max softmax: exp2 directly (masked/pad -> -inf -> 0); pack to bf16
        float lsum = 0.f;
        unsigned dw[8][2];
#pragma unroll
        for (int jt = 0; jt < 7; ++jt) {
            float p0 = exp2f(s[jt][0]);
            float p1 = exp2f(s[jt][1]);
            float p2 = exp2f(s[jt][2]);
            float p3 = exp2f(s[jt][3]);
            lsum += (p0 + p1) + (p2 + p3);
            dw[jt][0] = cvt2(p0, p1);
            dw[jt][1] = cvt2(p2, p3);
        }
        dw[7][0] = 0u; dw[7][1] = 0u;   // j = 112..127: zero B kills wrapped A garbage

        // PV with in-register P redistribution; vT linear stride 112
        f32x4 o0 = {0.f, 0.f, 0.f, 0.f}, o1 = {0.f, 0.f, 0.f, 0.f};
        __builtin_amdgcn_s_setprio(1);
#pragma unroll
        for (int jt4 = 0; jt4 < 4; ++jt4) {
            unsigned a0 = dw[2 * jt4][0],     a1 = dw[2 * jt4][1];
            unsigned b0 = dw[2 * jt4 + 1][0], b1 = dw[2 * jt4 + 1][1];
            unsigned xA0 = __shfl((int)a0, srcA), yA0 = __shfl((int)b0, srcA);
            unsigned xA1 = __shfl((int)a1, srcA), yA1 = __shfl((int)b1, srcA);
            unsigned xB0 = __shfl((int)a0, srcB), yB0 = __shfl((int)b0, srcB);
            unsigned xB1 = __shfl((int)a1, srcB), yB1 = __shfl((int)b1, srcB);
            uint32x4 pu = { phi ? yA0 : xA0, phi ? yA1 : xA1,
                            phi ? yB0 : xB0, phi ? yB1 : xB1 };
            bf16x8 pfrag = __builtin_bit_cast(bf16x8, pu);
            bf16x8 va = *(bf16x8*)(xv_w + (h * 32 + lc) * 112      + jt4 * 32 + l4 * 8);
            bf16x8 vb = *(bf16x8*)(xv_w + (h * 32 + 16 + lc) * 112 + jt4 * 32 + l4 * 8);
            o0 = __builtin_amdgcn_mfma_f32_16x16x32_bf16(va, pfrag, o0, 0, 0, 0);
            o1 = __builtin_amdgcn_mfma_f32_16x16x32_bf16(vb, pfrag, o1, 0, 0, 0);
        }
        __builtin_amdgcn_s_setprio(0);
        lsum += __shfl_xor(lsum, 16);
        lsum += __shfl_xor(lsum, 32);

        float inv = 1.0f / lsum;
        if (i_tok < 98) {
            uint2 h0, h1;
            h0.x = cvt2(o0[0] * inv, o0[1] * inv); h0.y = cvt2(o0[2] * inv, o0[3] * inv);
            h1.x = cvt2(o1[0] * inv, o1[1] * inv); h1.y = cvt2(o1[2] * inv, o1[3] * inv);
            *(uint2*)(q_w + swz(i_tok, h * 32 + l4 * 4)) = h0;        // O over q
            *(uint2*)(q_w + swz(i_tok, h * 32 + 16 + l4 * 4)) = h1;
        }
    }
    __syncthreads();

    // ---- Phase 3: y^T = Wproj @ O^T (O in q region) ----
    {
        const int ct = wv >> 1;
        bf16x8 pw[4];
#pragma unroll
        for (int kt = 0; kt < 4; ++kt)
            pw[kt] = *(const bf16x8*)(wproj + (ct * 16 + lc) * 128 + kt * 32 + l4 * 8);
        f32x4 pbias;
#pragma unroll
        for (int r = 0; r < 4; ++r) pbias[r] = proj_b[ct * 16 + l4 * 4 + r];

        float* ob = out + (size_t)b * 12544;
        const int tt0 = (wv & 1) ? 4 : 0, tt1 = (wv & 1) ? 7 : 4;
        for (int t = tt0; t < tt1; ++t) {
            f32x4 acc = pbias;
#pragma unroll
            for (int kt = 0; kt < 4; ++kt) {
                bf16x8 of = *(bf16x8*)(q_w + swz(t * 16 + lc, kt * 32 + l4 * 8));
                acc = __builtin_amdgcn_mfma_f32_16x16x32_bf16(pw[kt], of, acc, 0, 0, 0);
            }
            int tok = t * 16 + lc;
            if (tok < 98) {
                float4 st; st.x = acc[0]; st.y = acc[1]; st.z = acc[2]; st.w = acc[3];
                *(float4*)(ob + tok * 128 + ct * 16 + l4 * 4) = st;
            }
        }
    }
}

extern "C" void kernel_launch(void* const* d_in, const int* in_sizes, int n_in,
                              void* d_out, int out_size, void* d_ws, size_t ws_size,
                              hipStream_t stream) {
    const float* x       = (const float*)d_in[0];
    const float* qkv_w   = (const float*)d_in[1];
    const float* qkv_b   = (const float*)d_in[2];
    const float* rpb_tab = (const float*)d_in[3];
    const float* proj_w  = (const float*)d_in[4];
    const float* proj_b  = (const float*)d_in[5];
    const int*   rel_idx = (const int*)d_in[6];
    // d_in[7] (mask) unused: reproduced analytically into the tables.

    unsigned short* wqkv  = (unsigned short*)d_ws;                   // 98304 B
    unsigned short* wproj = (unsigned short*)((char*)d_ws + 98304);  // 32768 B
    void*           btab  = (void*)((char*)d_ws + 131072);           // bias table
    float*          out   = (float*)d_out;

    const bool big = ws_size >= (size_t)(131072 + 32 * 112 * 112 * 4);  // 1,736,704 B
    const int LDS_BYTES = 78880;

    if (big) {
        hipLaunchKernelGGL((prep_kernel<true>), dim3(1024), dim3(256), 0, stream,
                           qkv_w, proj_w, rpb_tab, rel_idx, wqkv, wproj, btab);
        (void)hipFuncSetAttribute((const void*)(swin_main<true>),
                                  hipFuncAttributeMaxDynamicSharedMemorySize, LDS_BYTES);
        hipLaunchKernelGGL((swin_main<true>), dim3(2048), dim3(1024), LDS_BYTES, stream,
                           x, qkv_b, proj_b, wqkv, wproj, btab, out);
    } else {
        hipLaunchKernelGGL((prep_kernel<false>), dim3(1024), dim3(256), 0, stream,
                           qkv_w, proj_w, rpb_tab, rel_idx, wqkv, wproj, btab);
        (void)hipFuncSetAttribute((const void*)(swin_main<false>),
                                  hipFuncAttributeMaxDynamicSharedMemorySize, LDS_BYTES);
        hipLaunchKernelGGL((swin_main<false>), dim3(2048), dim3(1024), LDS_BYTES, stream,
                           x, qkv_b, proj_b, wqkv, wproj, btab, out);
    }
}

// Round 14
// 124.133 us; speedup vs baseline: 1.1162x; 1.1162x over previous
//
#include <hip/hip_runtime.h>
#include <math.h>
#include <stdint.h>

// Video Swin shifted-window attention, fully fused, one block per window.
// Round 14: revert to R12 exactly (proven 124.9us): 78880B LDS -> 2
// independent blocks/CU (80% occupancy), register-carried V across the
// x->vT union barrier, no-max softmax, shfl-P PV, O-over-q union.
// R13's setprio+jt-streaming caused scratch spills under the 64-reg cap
// (WRITE_SIZE 125->182MB) -- removed. Only delta vs R12: prep grid 1024.

#define LOG2E   1.4426950408889634f
#define MASKNEG (-144.26950408889634f)   // -100 * LOG2E

typedef __attribute__((ext_vector_type(8)))  short    bf16x8;
typedef __attribute__((ext_vector_type(4)))  float    f32x4;
typedef __attribute__((ext_vector_type(4)))  unsigned uint32x4;

__device__ __forceinline__ unsigned short cvt1(float f) {
    __bf16 h = (__bf16)f;
    return __builtin_bit_cast(unsigned short, h);
}
__device__ __forceinline__ unsigned cvt2(float lo, float hi) {
    return (unsigned)cvt1(lo) | ((unsigned)cvt1(hi) << 16);
}

// token region code for the shifted-window mask (WIN=(2,7,7), SHIFT=(1,3,3))
__device__ __forceinline__ int tok_code(int t) {
    int pd = t / 49;
    int r  = t - pd * 49;
    int ph = r / 7;
    int pw = r - ph * 7;
    return (pd >= 1 ? 1 : 0) | (ph >= 4 ? 2 : 0) | (pw >= 4 ? 4 : 0);
}

__device__ __forceinline__ float mterm(unsigned pk, int sh, unsigned ci, unsigned cls) {
    return ((((pk >> sh) & 255u) ^ ci) & cls) ? MASKNEG : 0.f;
}

// XOR-swizzled element offset, [rows][128]-bf16 tiles (16B chunks)
__device__ __forceinline__ int swz(int row, int col) {
    return row * 128 + (((col >> 3) ^ (row & 7)) << 3) + (col & 7);
}

// ---------------- prep: weights -> bf16, bias tables ----------------
template<bool BIG>
__global__ void prep_kernel(const float* __restrict__ qkv_w,
                            const float* __restrict__ proj_w,
                            const float* __restrict__ rpb_table,
                            const int*   __restrict__ rel_index,
                            unsigned short* __restrict__ wqkv,
                            unsigned short* __restrict__ wproj,
                            void* __restrict__ btab) {
    int tid = blockIdx.x * blockDim.x + threadIdx.x;
    int stride = gridDim.x * blockDim.x;
    for (int i = tid; i < 384 * 128; i += stride) wqkv[i]  = cvt1(qkv_w[i]);
    for (int i = tid; i < 128 * 128; i += stride) wproj[i] = cvt1(proj_w[i]);
    if constexpr (BIG) {
        // bm[cls 8][h 4][i 112][j 112] f32: (bias + mask)*LOG2E; j>=98 -> -inf
        float* bm = (float*)btab;
        for (int idx = tid; idx < 32 * 112 * 112; idx += stride) {
            int ch = idx / 12544; int r = idx - ch * 12544;
            int i  = r / 112;     int j = r - i * 112;
            int cls = ch >> 2, h = ch & 3;
            float v;
            if (i < 98) {
                if (j < 98) {
                    float bias = rpb_table[rel_index[i * 98 + j] * 4 + h];
                    bool  msk  = (((unsigned)tok_code(i) ^ (unsigned)tok_code(j)) & (unsigned)cls) != 0;
                    v = bias * LOG2E + (msk ? MASKNEG : 0.f);
                } else v = -INFINITY;
            } else v = 0.f;
            bm[idx] = v;
        }
    } else {
        unsigned short* biasL = (unsigned short*)btab;
        for (int idx = tid; idx < 4 * 112 * 112; idx += stride) {
            int h = idx / 12544; int r = idx - h * 12544;
            int i = r / 112;     int j = r - i * 112;
            float v;
            if (i < 98) v = (j < 98) ? rpb_table[rel_index[i * 98 + j] * 4 + h] * LOG2E
                                     : -INFINITY;
            else v = 0.f;
            biasL[idx] = cvt1(v);
        }
    }
}

// ---------------- main fused kernel ----------------
template<bool BIG>
__global__ __launch_bounds__(1024, 8)
void swin_main(const float* __restrict__ x,
               const float* __restrict__ qkv_b,
               const float* __restrict__ proj_b,
               const unsigned short* __restrict__ wqkv,
               const unsigned short* __restrict__ wproj,
               const void* __restrict__ btab,
               float* __restrict__ out)
{
    extern __shared__ unsigned short lds[];
    unsigned short* q_w  = lds;            // q[98][128] swz; O overwrites
    unsigned short* k_w  = lds + 12544;    // k[98][128] swz
    unsigned short* xv_w = lds + 25088;    // x[112][128] swz -> vT[128][112] linear; +16 pad
    // total 39440 ush = 78880 B -> 2 blocks/CU

    const int b    = blockIdx.x;
    const int tid  = threadIdx.x;
    const int wv   = tid >> 6;    // 0..15
    const int lane = tid & 63;
    const int l4   = lane >> 4;   // 0..3
    const int lc   = lane & 15;   // 0..15

    // zero the 16-ush fragment-wrap pad (stale inf/NaN x 0 = NaN poison)
    if (tid < 8) *(unsigned*)(xv_w + 14336 + tid * 2) = 0u;

    // stage x -> xv_w swz (pad rows 98..111 zeroed)
    {
        const float* xb = x + (size_t)b * 12544;
#pragma unroll
        for (int i = 0; i < 4; ++i) {
            int idx = tid + i * 1024;
            if (idx >= 3584) break;
            int tok = idx >> 5;
            int c   = (idx & 31) << 2;
            float4 v;
            if (tok < 98) v = *(const float4*)(xb + tok * 128 + c);
            else { v.x = 0.f; v.y = 0.f; v.z = 0.f; v.w = 0.f; }
            uint2 hv; hv.x = cvt2(v.x, v.y); hv.y = cvt2(v.z, v.w);
            *(uint2*)(xv_w + swz(tok, c)) = hv;
        }
    }
    __syncthreads();

    // ---- Phase 1A: q,k tiles (wave ct: q<8 scaled, k>=8) ----
    {
        const int ct = wv;
        bf16x8 wf[4];
        f32x4  bias;
        const unsigned short* wrow = wqkv + (ct * 16 + lc) * 128;
#pragma unroll
        for (int kt = 0; kt < 4; ++kt) wf[kt] = *(const bf16x8*)(wrow + kt * 32 + l4 * 8);
#pragma unroll
        for (int r = 0; r < 4; ++r) bias[r] = qkv_b[ct * 16 + l4 * 4 + r];
        const bool  isq = (ct < 8);
        const float qs  = 0.17677669529663689f * LOG2E;
#pragma unroll
        for (int t = 0; t < 7; ++t) {
            bf16x8 xf[4];
#pragma unroll
            for (int kt = 0; kt < 4; ++kt)
                xf[kt] = *(bf16x8*)(xv_w + swz(t * 16 + lc, kt * 32 + l4 * 8));
            f32x4 acc = bias;
#pragma unroll
            for (int kt = 0; kt < 4; ++kt)
                acc = __builtin_amdgcn_mfma_f32_16x16x32_bf16(wf[kt], xf[kt], acc, 0, 0, 0);
            int tok = t * 16 + lc;
            if (tok < 98) {
                if (isq) {
                    uint2 hv; hv.x = cvt2(acc[0] * qs, acc[1] * qs); hv.y = cvt2(acc[2] * qs, acc[3] * qs);
                    *(uint2*)(q_w + swz(tok, ct * 16 + l4 * 4)) = hv;
                } else {
                    uint2 hv; hv.x = cvt2(acc[0], acc[1]); hv.y = cvt2(acc[2], acc[3]);
                    *(uint2*)(k_w + swz(tok, (ct - 8) * 16 + l4 * 4)) = hv;
                }
            }
        }
    }

    // ---- Phase 1B: v tiles into registers (x still live) ----
    f32x4 vacc[4];
    const int vd = (wv >> 1) * 16;
    const int t0 = (wv & 1) ? 4 : 0;
    const int nt = (wv & 1) ? 3 : 4;
    {
        bf16x8 wf2[4];
        const unsigned short* wrow2 = wqkv + (256 + vd + lc) * 128;
#pragma unroll
        for (int kt = 0; kt < 4; ++kt) wf2[kt] = *(const bf16x8*)(wrow2 + kt * 32 + l4 * 8);
        f32x4 bias2;
#pragma unroll
        for (int r = 0; r < 4; ++r) bias2[r] = qkv_b[256 + vd + l4 * 4 + r];
#pragma unroll
        for (int ti = 0; ti < 4; ++ti) {
            if (ti >= nt) break;
            int t = t0 + ti;
            bf16x8 xf[4];
#pragma unroll
            for (int kt = 0; kt < 4; ++kt)
                xf[kt] = *(bf16x8*)(xv_w + swz(t * 16 + lc, kt * 32 + l4 * 8));
            f32x4 acc = bias2;
#pragma unroll
            for (int kt = 0; kt < 4; ++kt)
                acc = __builtin_amdgcn_mfma_f32_16x16x32_bf16(wf2[kt], xf[kt], acc, 0, 0, 0);
            vacc[ti] = acc;
        }
    }
    __syncthreads();   // all x reads complete

    // ---- Phase 1C: vT[128][112] linear over the x region ----
    {
#pragma unroll
        for (int ti = 0; ti < 4; ++ti) {
            if (ti >= nt) break;
            int tok = (t0 + ti) * 16 + lc;
            const int rb = vd + l4 * 4;
            xv_w[(rb + 0) * 112 + tok] = cvt1(vacc[ti][0]);
            xv_w[(rb + 1) * 112 + tok] = cvt1(vacc[ti][1]);
            xv_w[(rb + 2) * 112 + tok] = cvt1(vacc[ti][2]);
            xv_w[(rb + 3) * 112 + tok] = cvt1(vacc[ti][3]);
        }
    }
    __syncthreads();

    // ---- Phase 2: attention. 28 tasks over 16 waves, 2 passes (shfl-P) ----
    const int wi  = b & 255;
    const unsigned int cls =
        ((wi >> 6) == 3 ? 1u : 0u) | (((wi >> 3) & 7) == 7 ? 2u : 0u) | ((wi & 7) == 7 ? 4u : 0u);

    unsigned int jcp[7];   // packed region codes (small path only)
    if constexpr (!BIG) {
#pragma unroll
        for (int jt = 0; jt < 7; ++jt) {
            int jb = jt * 16 + l4 * 4;
            unsigned int p = 0;
#pragma unroll
            for (int r = 0; r < 4; ++r) p |= (unsigned)tok_code(jb + r < 98 ? jb + r : 0) << (8 * r);
            jcp[jt] = p;
        }
    }

    const int  srcA = ((l4 & 1) * 2) * 16 + lc;   // P-redistribution source lanes
    const int  srcB = srcA + 16;
    const bool phi  = (l4 >> 1) != 0;

    for (int pass = 0; pass < 2; ++pass) {
        int task = wv + (pass << 4);
        if (task >= 28) break;
        int h  = task / 7;
        int it = task - h * 7;
        const int i_tok = it * 16 + lc;
        const bf16x8 qfrag = *(bf16x8*)(q_w + swz(i_tok, h * 32 + l4 * 8));

        f32x4 cvec[7];
        if constexpr (BIG) {
            const float* bmrow = (const float*)btab + ((size_t)((int)cls * 4 + h) * 112 + i_tok) * 112;
#pragma unroll
            for (int jt = 0; jt < 7; ++jt)
                cvec[jt] = *(const f32x4*)(bmrow + jt * 16 + l4 * 4);
        } else {
            const unsigned short* brow = (const unsigned short*)btab + (h * 112 + i_tok) * 112;
            const unsigned int ci = (unsigned)tok_code(i_tok < 98 ? i_tok : 0);
            ushort4 bb[7];
#pragma unroll
            for (int jt = 0; jt < 7; ++jt)
                bb[jt] = *(const ushort4*)(brow + jt * 16 + l4 * 4);
#pragma unroll
            for (int jt = 0; jt < 7; ++jt) {
                cvec[jt][0] = __builtin_bit_cast(float, (unsigned)bb[jt].x << 16) + mterm(jcp[jt], 0,  ci, cls);
                cvec[jt][1] = __builtin_bit_cast(float, (unsigned)bb[jt].y << 16) + mterm(jcp[jt], 8,  ci, cls);
                cvec[jt][2] = __builtin_bit_cast(float, (unsigned)bb[jt].z << 16) + mterm(jcp[jt], 16, ci, cls);
                cvec[jt][3] = __builtin_bit_cast(float, (unsigned)bb[jt].w << 16) + mterm(jcp[jt], 24, ci, cls);
            }
        }

        f32x4 s[7];
#pragma unroll
        for (int jt = 0; jt < 7; ++jt) {
            bf16x8 kfrag = *(bf16x8*)(k_w + swz(jt * 16 + lc, h * 32 + l4 * 8));
            s[jt] = __builtin_amdgcn_mfma_f32_16x16x32_bf16(kfrag, qfrag, cvec[jt], 0, 0, 0);
        }

        // no-max softmax: exp2 directly (masked/pad -> -inf -> 0); pack to bf16
        float lsum = 0.f;
        unsigned dw[8][2];
#pragma unroll
        for (int jt = 0; jt < 7; ++jt) {
            float p0 = exp2f(s[jt][0]);
            float p1 = exp2f(s[jt][1]);
            float p2 = exp2f(s[jt][2]);
            float p3 = exp2f(s[jt][3]);
            lsum += (p0 + p1) + (p2 + p3);
            dw[jt][0] = cvt2(p0, p1);
            dw[jt][1] = cvt2(p2, p3);
        }
        dw[7][0] = 0u; dw[7][1] = 0u;   // j = 112..127: zero B kills wrapped A garbage

        // PV with in-register P redistribution; vT linear stride 112
        f32x4 o0 = {0.f, 0.f, 0.f, 0.f}, o1 = {0.f, 0.f, 0.f, 0.f};
#pragma unroll
        for (int jt4 = 0; jt4 < 4; ++jt4) {
            unsigned a0 = dw[2 * jt4][0],     a1 = dw[2 * jt4][1];
            unsigned b0 = dw[2 * jt4 + 1][0], b1 = dw[2 * jt4 + 1][1];
            unsigned xA0 = __shfl((int)a0, srcA), yA0 = __shfl((int)b0, srcA);
            unsigned xA1 = __shfl((int)a1, srcA), yA1 = __shfl((int)b1, srcA);
            unsigned xB0 = __shfl((int)a0, srcB), yB0 = __shfl((int)b0, srcB);
            unsigned xB1 = __shfl((int)a1, srcB), yB1 = __shfl((int)b1, srcB);
            uint32x4 pu = { phi ? yA0 : xA0, phi ? yA1 : xA1,
                            phi ? yB0 : xB0, phi ? yB1 : xB1 };
            bf16x8 pfrag = __builtin_bit_cast(bf16x8, pu);
            bf16x8 va = *(bf16x8*)(xv_w + (h * 32 + lc) * 112      + jt4 * 32 + l4 * 8);
            bf16x8 vb = *(bf16x8*)(xv_w + (h * 32 + 16 + lc) * 112 + jt4 * 32 + l4 * 8);
            o0 = __builtin_amdgcn_mfma_f32_16x16x32_bf16(va, pfrag, o0, 0, 0, 0);
            o1 = __builtin_amdgcn_mfma_f32_16x16x32_bf16(vb, pfrag, o1, 0, 0, 0);
        }
        lsum += __shfl_xor(lsum, 16);
        lsum += __shfl_xor(lsum, 32);

        float inv = 1.0f / lsum;
        if (i_tok < 98) {
            uint2 h0, h1;
            h0.x = cvt2(o0[0] * inv, o0[1] * inv); h0.y = cvt2(o0[2] * inv, o0[3] * inv);
            h1.x = cvt2(o1[0] * inv, o1[1] * inv); h1.y = cvt2(o1[2] * inv, o1[3] * inv);
            *(uint2*)(q_w + swz(i_tok, h * 32 + l4 * 4)) = h0;        // O over q
            *(uint2*)(q_w + swz(i_tok, h * 32 + 16 + l4 * 4)) = h1;
        }
    }
    __syncthreads();

    // ---- Phase 3: y^T = Wproj @ O^T (O in q region) ----
    {
        const int ct = wv >> 1;
        bf16x8 pw[4];
#pragma unroll
        for (int kt = 0; kt < 4; ++kt)
            pw[kt] = *(const bf16x8*)(wproj + (ct * 16 + lc) * 128 + kt * 32 + l4 * 8);
        f32x4 pbias;
#pragma unroll
        for (int r = 0; r < 4; ++r) pbias[r] = proj_b[ct * 16 + l4 * 4 + r];

        float* ob = out + (size_t)b * 12544;
        const int tt0 = (wv & 1) ? 4 : 0, tt1 = (wv & 1) ? 7 : 4;
        for (int t = tt0; t < tt1; ++t) {
            f32x4 acc = pbias;
#pragma unroll
            for (int kt = 0; kt < 4; ++kt) {
                bf16x8 of = *(bf16x8*)(q_w + swz(t * 16 + lc, kt * 32 + l4 * 8));
                acc = __builtin_amdgcn_mfma_f32_16x16x32_bf16(pw[kt], of, acc, 0, 0, 0);
            }
            int tok = t * 16 + lc;
            if (tok < 98) {
                float4 st; st.x = acc[0]; st.y = acc[1]; st.z = acc[2]; st.w = acc[3];
                *(float4*)(ob + tok * 128 + ct * 16 + l4 * 4) = st;
            }
        }
    }
}

extern "C" void kernel_launch(void* const* d_in, const int* in_sizes, int n_in,
                              void* d_out, int out_size, void* d_ws, size_t ws_size,
                              hipStream_t stream) {
    const float* x       = (const float*)d_in[0];
    const float* qkv_w   = (const float*)d_in[1];
    const float* qkv_b   = (const float*)d_in[2];
    const float* rpb_tab = (const float*)d_in[3];
    const float* proj_w  = (const float*)d_in[4];
    const float* proj_b  = (const float*)d_in[5];
    const int*   rel_idx = (const int*)d_in[6];
    // d_in[7] (mask) unused: reproduced analytically into the tables.

    unsigned short* wqkv  = (unsigned short*)d_ws;                   // 98304 B
    unsigned short* wproj = (unsigned short*)((char*)d_ws + 98304);  // 32768 B
    void*           btab  = (void*)((char*)d_ws + 131072);           // bias table
    float*          out   = (float*)d_out;

    const bool big = ws_size >= (size_t)(131072 + 32 * 112 * 112 * 4);  // 1,736,704 B
    const int LDS_BYTES = 78880;

    if (big) {
        hipLaunchKernelGGL((prep_kernel<true>), dim3(1024), dim3(256), 0, stream,
                           qkv_w, proj_w, rpb_tab, rel_idx, wqkv, wproj, btab);
        (void)hipFuncSetAttribute((const void*)(swin_main<true>),
                                  hipFuncAttributeMaxDynamicSharedMemorySize, LDS_BYTES);
        hipLaunchKernelGGL((swin_main<true>), dim3(2048), dim3(1024), LDS_BYTES, stream,
                           x, qkv_b, proj_b, wqkv, wproj, btab, out);
    } else {
        hipLaunchKernelGGL((prep_kernel<false>), dim3(1024), dim3(256), 0, stream,
                           qkv_w, proj_w, rpb_tab, rel_idx, wqkv, wproj, btab);
        (void)hipFuncSetAttribute((const void*)(swin_main<false>),
                                  hipFuncAttributeMaxDynamicSharedMemorySize, LDS_BYTES);
        hipLaunchKernelGGL((swin_main<false>), dim3(2048), dim3(1024), LDS_BYTES, stream,
                           x, qkv_b, proj_b, wqkv, wproj, btab, out);
    }
}